// Round 1
// 22.080 us; speedup vs baseline: 1.0239x; 1.0239x over previous
//
#include <hip/hip_runtime.h>

#define HO 124
#define WO 124

typedef float f2 __attribute__((ext_vector_type(2)));
static __device__ __forceinline__ f2 fma2(f2 a, f2 b, f2 c) {
  return __builtin_elementwise_fma(a, b, c);
}
#define FSQRT(x) __builtin_amdgcn_sqrtf(x)
#define FLOG10(x) (0.30102999566398120f * __builtin_amdgcn_logf(x))

constexpr float K1 = 0.80901699437494745f;  // cos36
constexpr float K2 = 0.30901699437494742f;  // cos72
constexpr float G1 = 0.58778525229247314f;  // sin36
constexpr float G2 = 0.95105651629515357f;  // sin72

// Folded band-weight table at compile time (band model verified R11:
// torch-style floor/clamp binning; corners->band5; knife {3,6}x{3,6} ->
// (1,1,2); counts [4,11,17,20,36,12]).
struct Tbl { float v[360]; };
constexpr Tbl mk_wv() {
  Tbl t{};
  int band[100] = {};
  int cnt[6] = {0, 0, 0, 0, 0, 0};
  for (int i = 0; i < 10; ++i)
    for (int j = 0; j < 10; ++j) {
      const int u = (2 * i - 9) < 0 ? (9 - 2 * i) : (2 * i - 9);
      const int v = (2 * j - 9) < 0 ? (9 - 2 * j) : (2 * j - 9);
      const int m = 2 * (u * u + v * v);
      int b = -1;
      for (int k = 0; k < 6; ++k)
        if (m >= 9 * k * k && m < 9 * (k + 1) * (k + 1)) b = k;
      if (u == 3 && v == 3) b = (i == 6 && j == 6) ? 2 : 1;
      if (m == 324) b = 5;
      band[i * 10 + j] = b;
      if (b >= 0) cnt[b]++;
    }
  for (int ky = 0; ky < 6; ++ky)
    for (int kx = 0; kx < 10; ++kx)
      for (int b = 0; b < 6; ++b) {
        float w = 0.0f;
        const int sp = ((ky + 5) % 10) * 10 + (kx + 5) % 10;
        if (band[sp] == b) w += 0.1f / (float)cnt[b];
        if (ky >= 1 && ky <= 4) {
          const int sp2 = ((15 - ky) % 10) * 10 + (15 - kx) % 10;
          if (band[sp2] == b) w += 0.1f / (float)cnt[b];
        }
        t.v[(ky * 10 + kx) * 6 + b] = w;
      }
  return t;
}
__device__ constexpr Tbl WVT = mk_wv();

#define ACCW(cell, amp)                                        \
  {                                                            \
    _Pragma("unroll")                                          \
    for (int b = 0; b < 6; ++b)                                \
      if (WVT.v[(cell) * 6 + b] != 0.0f)                       \
        acc[b] = fmaf((amp), WVT.v[(cell) * 6 + b], acc[b]);   \
  }
#define ACCW2(c1, c2, amp)                                     \
  {                                                            \
    _Pragma("unroll")                                          \
    for (int b = 0; b < 6; ++b) {                              \
      const float ws = WVT.v[(c1) * 6 + b] + WVT.v[(c2) * 6 + b]; \
      if (ws != 0.0f) acc[b] = fmaf((amp), ws, acc[b]);        \
    }                                                          \
  }

// Single-pass. THIS ROUND (occupancy experiment): LDS shaved 33,664 ->
// 32,000 B (tile stride 44->40, Tcp stride 42->40; both keep 16B-aligned
// b128 stores/merged reads and <=2-way bank aliasing) so 5 blocks/CU fit;
// __launch_bounds__(256,5) raises residency 16 -> 20 waves/CU.
__global__ __launch_bounds__(256, 5) void lfs_main(const float* __restrict__ x,
                                                   float* __restrict__ out) {
  __shared__ __attribute__((aligned(16))) float tile[40 * 40];
  __shared__ __attribute__((aligned(16))) f2 Tcp[4 * 16 * 40];  // ky1..4 {re,im}
  __shared__ __attribute__((aligned(16))) f2 Trr2[16 * 40];     // {ky0, ky5}
  const int tid = threadIdx.x;
  const int bx = blockIdx.x, by = blockIdx.y, bb = blockIdx.z;

  const int oy0 = by * 32, ox0 = bx * 32;
  const float* xr = x + (size_t)bb * 3 * 65536;
  const float* xg = xr + 65536;
  const float* xb = xr + 131072;
  const bool xfull = (bx < 7);
  for (int i = tid; i < 400; i += 256) {
    const int r = i / 10, c4 = i % 10;
    const int gy = oy0 + r;
    float4 g = make_float4(0.f, 0.f, 0.f, 0.f);
    if (gy < 256 && (c4 < 8 || xfull)) {
      const int off = gy * 256 + ox0 + c4 * 4;
      const float4 a = *reinterpret_cast<const float4*>(xr + off);
      const float4 b = *reinterpret_cast<const float4*>(xg + off);
      const float4 d = *reinterpret_cast<const float4*>(xb + off);
      g.x = fmaf(0.2989f, a.x, fmaf(0.587f, b.x, 0.114f * d.x));
      g.y = fmaf(0.2989f, a.y, fmaf(0.587f, b.y, 0.114f * d.y));
      g.z = fmaf(0.2989f, a.z, fmaf(0.587f, b.z, 0.114f * d.z));
      g.w = fmaf(0.2989f, a.w, fmaf(0.587f, b.w, 0.114f * d.w));
    }
    *reinterpret_cast<float4*>(&tile[r * 40 + c4 * 4]) = g;
  }
  __syncthreads();

  // Stage 1: 320 column-PAIR transforms (16 rows x 20 pairs), f2 lanes =
  // two adjacent columns, all 6 ky.
  for (int a = tid; a < 320; a += 256) {
    const int r = a / 20, cp = a % 20;
    const float* tb0 = &tile[(2 * r) * 40 + 2 * cp];
    f2 col[10];
#pragma unroll
    for (int y = 0; y < 10; ++y)
      col[y] = *reinterpret_cast<const f2*>(&tb0[y * 40]);
    const f2 E = col[0] + col[5], F = col[0] - col[5];
    const f2 P1 = col[1] + col[9], M1 = col[1] - col[9];
    const f2 P2 = col[2] + col[8], M2 = col[2] - col[8];
    const f2 P3 = col[3] + col[7], M3 = col[3] - col[7];
    const f2 P4 = col[4] + col[6], M4 = col[4] - col[6];
    const f2 U1 = P1 - P4, U2 = P2 - P3;
    const f2 V1 = P1 + P4, V2 = P2 + P3;
    const f2 W1 = M1 + M4, W2 = M2 + M3;
    const f2 Z1 = M1 - M4, Z2 = M2 - M3;
    const f2 k0 = E + V1 + V2, k5 = F - U1 + U2;
    const f2 sr1 = fma2(U1, (f2){K1, K1}, fma2(U2, (f2){K2, K2}, F));
    const f2 si1 = fma2(W1, (f2){-G1, -G1}, W2 * (f2){-G2, -G2});
    const f2 sr2 = fma2(V1, (f2){K2, K2}, fma2(V2, (f2){-K1, -K1}, E));
    const f2 si2 = fma2(Z1, (f2){-G2, -G2}, Z2 * (f2){-G1, -G1});
    const f2 sr3 = fma2(U1, (f2){-K2, -K2}, fma2(U2, (f2){-K1, -K1}, F));
    const f2 si3 = fma2(W1, (f2){-G2, -G2}, W2 * (f2){G1, G1});
    const f2 sr4 = fma2(V1, (f2){-K1, -K1}, fma2(V2, (f2){K2, K2}, E));
    const f2 si4 = fma2(Z1, (f2){-G1, -G1}, Z2 * (f2){G2, G2});
    // Interleaved stores: per column {ky0,ky5} / {re,im}; two columns = b128.
    *reinterpret_cast<float4*>(&Trr2[r * 40 + 2 * cp]) =
        make_float4(k0.x, k5.x, k0.y, k5.y);
    *reinterpret_cast<float4*>(&Tcp[(0 * 16 + r) * 40 + 2 * cp]) =
        make_float4(sr1.x, si1.x, sr1.y, si1.y);
    *reinterpret_cast<float4*>(&Tcp[(1 * 16 + r) * 40 + 2 * cp]) =
        make_float4(sr2.x, si2.x, sr2.y, si2.y);
    *reinterpret_cast<float4*>(&Tcp[(2 * 16 + r) * 40 + 2 * cp]) =
        make_float4(sr3.x, si3.x, sr3.y, si3.y);
    *reinterpret_cast<float4*>(&Tcp[(3 * 16 + r) * 40 + 2 * cp]) =
        make_float4(sr4.x, si4.x, sr4.y, si4.y);
  }
  __syncthreads();

  const int tx = tid & 15, ty = tid >> 4;
  const int h = by * 16 + ty, w = bx * 16 + tx;
  const bool valid = (h < HO) && (w < WO);

  if (valid) {
    float acc[6] = {0.f, 0.f, 0.f, 0.f, 0.f, 0.f};

    // ---- Real paths ky0 & ky5, packed as f2 lanes {ky0, ky5} ----
    {
      const f2* tbr = &Trr2[ty * 40 + 2 * tx];
      f2 T_[10];
#pragma unroll
      for (int q = 0; q < 10; ++q) T_[q] = tbr[q];
      const f2 E = T_[0] + T_[5], F = T_[0] - T_[5];
      const f2 P1 = T_[1] + T_[9], M1 = T_[1] - T_[9];
      const f2 P2 = T_[2] + T_[8], M2 = T_[2] - T_[8];
      const f2 P3 = T_[3] + T_[7], M3 = T_[3] - T_[7];
      const f2 P4 = T_[4] + T_[6], M4 = T_[4] - T_[6];
      const f2 U1 = P1 - P4, U2 = P2 - P3;
      const f2 V1 = P1 + P4, V2 = P2 + P3;
      const f2 W1 = M1 + M4, W2 = M2 + M3;
      const f2 Z1 = M1 - M4, Z2 = M2 - M3;
      {
        const f2 A = E + V1 + V2;
        ACCW(0, fabsf(A.x));
        ACCW(50, fabsf(A.y));
      }
      {
        const f2 A = F - U1 + U2;
        ACCW(5, fabsf(A.x));
        ACCW(55, fabsf(A.y));
      }
      {
        const f2 A = fma2((f2){K1, K1}, U1, fma2((f2){K2, K2}, U2, F));
        const f2 D = fma2((f2){G1, G1}, W1, (f2){G2, G2} * W2);
        const f2 s = fma2(A, A, D * D);
        ACCW2(1, 9, FSQRT(s.x));
        ACCW2(51, 59, FSQRT(s.y));
      }
      {
        const f2 A = fma2((f2){K2, K2}, V1, fma2((f2){-K1, -K1}, V2, E));
        const f2 D = fma2((f2){G2, G2}, Z1, (f2){G1, G1} * Z2);
        const f2 s = fma2(A, A, D * D);
        ACCW2(2, 8, FSQRT(s.x));
        ACCW2(52, 58, FSQRT(s.y));
      }
      {
        const f2 A = fma2((f2){-K2, -K2}, U1, fma2((f2){-K1, -K1}, U2, F));
        const f2 D = fma2((f2){G2, G2}, W1, (f2){-G1, -G1} * W2);
        const f2 s = fma2(A, A, D * D);
        ACCW2(3, 7, FSQRT(s.x));
        ACCW2(53, 57, FSQRT(s.y));
      }
      {
        const f2 A = fma2((f2){-K1, -K1}, V1, fma2((f2){K2, K2}, V2, E));
        const f2 D = fma2((f2){G1, G1}, Z1, (f2){-G2, -G2} * Z2);
        const f2 s = fma2(A, A, D * D);
        ACCW2(4, 6, FSQRT(s.x));
        ACCW2(54, 56, FSQRT(s.y));
      }
    }

    // ---- Complex-ky paths: planes p=0..3 -> ky=1..4 ----
#pragma unroll
    for (int p = 0; p < 4; ++p) {
      const int ky = 1 + p;
      const f2* tbc = &Tcp[(p * 16 + ty) * 40 + 2 * tx];
      f2 T_[10];
#pragma unroll
      for (int q = 0; q < 10; ++q) T_[q] = tbc[q];
      const f2 EE = T_[0] + T_[5], FF = T_[0] - T_[5];
      const f2 PQ1 = T_[1] + T_[9], MN1 = T_[1] - T_[9];
      const f2 PQ2 = T_[2] + T_[8], MN2 = T_[2] - T_[8];
      const f2 PQ3 = T_[3] + T_[7], MN3 = T_[3] - T_[7];
      const f2 PQ4 = T_[4] + T_[6], MN4 = T_[4] - T_[6];
      const f2 UU1 = PQ1 - PQ4, UU2 = PQ2 - PQ3;
      const f2 VV1 = PQ1 + PQ4, VV2 = PQ2 + PQ3;
      const f2 WW1 = MN1 + MN4, WW2 = MN2 + MN3;
      const f2 ZZ1 = MN1 - MN4, ZZ2 = MN2 - MN3;
      {
        const f2 AC = EE + VV1 + VV2;
        ACCW(ky * 10 + 0, FSQRT(fmaf(AC.x, AC.x, AC.y * AC.y)));
      }
      {
        const f2 AC = FF - UU1 + UU2;
        ACCW(ky * 10 + 5, FSQRT(fmaf(AC.x, AC.x, AC.y * AC.y)));
      }
#define CPLX_PAIR(kx, AC_, DB_)                                         \
  {                                                                     \
    const f2 AC = (AC_);                                                \
    const f2 DB = (DB_);                                                \
    {                                                                   \
      const float fr = AC.x + DB.y, fi = AC.y - DB.x;                   \
      ACCW(ky * 10 + (kx), FSQRT(fmaf(fr, fr, fi * fi)));               \
    }                                                                   \
    {                                                                   \
      const float fr = AC.x - DB.y, fi = AC.y + DB.x;                   \
      ACCW(ky * 10 + 10 - (kx), FSQRT(fmaf(fr, fr, fi * fi)));          \
    }                                                                   \
  }
      CPLX_PAIR(1,
                fma2(UU1, (f2){K1, K1}, fma2(UU2, (f2){K2, K2}, FF)),
                fma2(WW1, (f2){G1, G1}, WW2 * (f2){G2, G2}));
      CPLX_PAIR(2,
                fma2(VV1, (f2){K2, K2}, fma2(VV2, (f2){-K1, -K1}, EE)),
                fma2(ZZ1, (f2){G2, G2}, ZZ2 * (f2){G1, G1}));
      CPLX_PAIR(3,
                fma2(UU1, (f2){-K2, -K2}, fma2(UU2, (f2){-K1, -K1}, FF)),
                fma2(WW1, (f2){G2, G2}, WW2 * (f2){-G1, -G1}));
      CPLX_PAIR(4,
                fma2(VV1, (f2){-K1, -K1}, fma2(VV2, (f2){K2, K2}, EE)),
                fma2(ZZ1, (f2){G1, G1}, ZZ2 * (f2){-G2, -G2}));
#undef CPLX_PAIR
    }

    const size_t ob = ((size_t)bb * 6) * (HO * WO) + (size_t)h * WO + w;
#pragma unroll
    for (int b = 0; b < 6; ++b)
      out[ob + (size_t)b * (HO * WO)] = FLOG10(acc[b] + 1e-6f);
  }
}

extern "C" void kernel_launch(void* const* d_in, const int* in_sizes, int n_in,
                              void* d_out, int out_size, void* d_ws,
                              size_t ws_size, hipStream_t stream) {
  (void)in_sizes; (void)n_in; (void)out_size; (void)d_ws; (void)ws_size;
  const float* x = (const float*)d_in[0];
  float* out = (float*)d_out;
  lfs_main<<<dim3(8, 8, 32), 256, 0, stream>>>(x, out);
}